// Round 6
// baseline (656.562 us; speedup 1.0000x reference)
//
#include <hip/hip_runtime.h>
#include <hip/hip_bf16.h>

#define B_    2
#define S_    1024
#define HID_  4096
#define H_    32
#define HKV_  8
#define HD_   128

typedef __attribute__((ext_vector_type(8))) short   bf16x8_t;
typedef __attribute__((ext_vector_type(4))) float   f32x4_t;

__device__ __forceinline__ unsigned short f2bf(float f) {
    union { float f; unsigned u; } v; v.f = f;
    unsigned r = v.u + 0x7fffu + ((v.u >> 16) & 1u);
    return (unsigned short)(r >> 16);
}
__device__ __forceinline__ float bf2f(unsigned short u) {
    union { unsigned u; float f; } v; v.u = ((unsigned)u) << 16;
    return v.f;
}

__device__ __forceinline__ void gload_lds16(const void* g, void* l) {
    __builtin_amdgcn_global_load_lds(
        (const __attribute__((address_space(1))) unsigned int*)g,
        (__attribute__((address_space(3))) unsigned int*)l, 16, 0, 0);
}

// 32x32 transpose+convert tile body (W fp32 [K][ldW] -> Wt bf16 [n][4096])
__device__ __forceinline__ void tcvt_body(const float* __restrict__ W,
                                          unsigned short* __restrict__ Wt,
                                          int ldW, int nb, int kb,
                                          unsigned short (*L)[36], int t) {
    {
        int kr = t >> 3, nc = (t & 7) * 4;
        float4 v = *reinterpret_cast<const float4*>(&W[(size_t)(kb * 32 + kr) * ldW + nb * 32 + nc]);
        L[nc + 0][kr] = f2bf(v.x);
        L[nc + 1][kr] = f2bf(v.y);
        L[nc + 2][kr] = f2bf(v.z);
        L[nc + 3][kr] = f2bf(v.w);
    }
    __syncthreads();
    {
        int nr = t >> 3, kc = (t & 7) * 4;
        uint2 o;
        o.x = (unsigned)L[nr][kc + 0] | ((unsigned)L[nr][kc + 1] << 16);
        o.y = (unsigned)L[nr][kc + 2] | ((unsigned)L[nr][kc + 3] << 16);
        *reinterpret_cast<uint2*>(&Wt[(size_t)(nb * 32 + nr) * 4096 + kb * 32 + kc]) = o;
    }
}

// ---------------- prep: cvt(x) | tcvt(wq) | tcvt(wk) | tcvt(wv) | rope table ----------------
__global__ __launch_bounds__(256) void prep(
    const float* __restrict__ x,  const float* __restrict__ wq,
    const float* __restrict__ wk, const float* __restrict__ wv,
    const int* __restrict__ start_pos,
    unsigned short* __restrict__ xb, unsigned short* __restrict__ wqT,
    unsigned short* __restrict__ wkvT, float* __restrict__ tb)
{
    const int bid = blockIdx.x;
    const int t   = threadIdx.x;
    if (bid < 8192) {                         // x fp32 -> bf16  (2048*4096/4 float4s)
        int i = bid * 256 + t;
        float4 v = reinterpret_cast<const float4*>(x)[i];
        uint2 p;
        p.x = (unsigned)f2bf(v.x) | ((unsigned)f2bf(v.y) << 16);
        p.y = (unsigned)f2bf(v.z) | ((unsigned)f2bf(v.w) << 16);
        reinterpret_cast<uint2*>(xb)[i] = p;
        return;
    }
    if (bid >= 32768) {                       // rope table: 512 blocks = 2048 tok * 64 d
        int i = (bid - 32768) * 256 + t;
        int d = i & 63;
        int tok = i >> 6;
        int s = tok & (S_ - 1);
        int b = tok >> 10;
        float pos = (float)(start_pos[b] + s);
        float freq = __expf(-(float)d * (9.210340371976184f / 64.f));   // 10000^(-d/64)
        float ang = pos * freq;
        tb[tok * 128 + d]      = cosf(ang);
        tb[tok * 128 + 64 + d] = sinf(ang);
        return;
    }
    __shared__ unsigned short L[32][36];
    if (bid < 24576) {                        // wq^T (128 x 128 tiles)
        int q = bid - 8192;
        tcvt_body(wq, wqT, 4096, q & 127, q >> 7, L, t);
    } else if (bid < 28672) {                 // wk^T (32 x 128)
        int q = bid - 24576;
        tcvt_body(wk, wkvT, 1024, q & 31, q >> 5, L, t);
    } else {                                  // wv^T (32 x 128)
        int q = bid - 28672;
        tcvt_body(wv, wkvT + (size_t)1024 * 4096, 1024, q & 31, q >> 5, L, t);
    }
}

// ---------------- fused QKV GEMM (N=6144) + RoPE epilogue for Q/K, V^T routing ----------------
__global__ __launch_bounds__(256) void gemm_qkv(
    const unsigned short* __restrict__ A,      // xb [2048][4096]
    const unsigned short* __restrict__ BtQ,    // wqT [4096][4096]
    const unsigned short* __restrict__ BtKV,   // wkvT [2048][4096]
    const float* __restrict__ tb,              // rope table [2048][128]
    unsigned short* __restrict__ Qb,           // [2048][4096] roped
    unsigned short* __restrict__ Kb,           // [2048][1024] roped
    unsigned short* __restrict__ VT,           // [2048][1024] transposed V
    int K)
{
    __shared__ unsigned short LDS[16384];      // As[2][4096] | Bs[2][4096]; flat 128x128 in epilogue
    unsigned short* As0 = LDS;
    unsigned short* Bs0 = LDS + 8192;
    const int tid  = threadIdx.x;
    const int lane = tid & 63;
    const int w    = tid >> 6;
    const int wm   = w >> 1, wn = w & 1;
    const int r    = lane & 15, g = lane >> 4;

    const int nwg = gridDim.x * gridDim.y;
    const int D   = blockIdx.y * gridDim.x + blockIdx.x;
    const int L   = (D & 7) * (nwg >> 3) + (D >> 3);
    const int m0  = (L / gridDim.x) * 128, n0 = (L % gridDim.x) * 128;

    const unsigned short* Brow = (n0 < 4096) ? (BtQ + (size_t)n0 * K)
                                             : (BtKV + (size_t)(n0 - 4096) * K);

    const int c0 = w * 128 + lane;
    const int c1 = c0 + 64;
    const int r0 = c0 >> 2, col0 = (((c0 & 3) ^ (r0 & 3)) << 3);
    const int r1 = c1 >> 2, col1 = (((c1 & 3) ^ (r1 & 3)) << 3);
    const int sw = (g ^ (r & 3)) << 3;

    const f32x4_t zero = {0.f, 0.f, 0.f, 0.f};
    f32x4_t acc[4][4];
#pragma unroll
    for (int i = 0; i < 4; ++i)
#pragma unroll
        for (int j = 0; j < 4; ++j) acc[i][j] = zero;

    gload_lds16(&A   [(size_t)(m0 + r0) * K + col0], &As0[(w * 2 + 0) * 512]);
    gload_lds16(&A   [(size_t)(m0 + r1) * K + col1], &As0[(w * 2 + 1) * 512]);
    gload_lds16(&Brow[(size_t)r0 * K + col0],        &Bs0[(w * 2 + 0) * 512]);
    gload_lds16(&Brow[(size_t)r1 * K + col1],        &Bs0[(w * 2 + 1) * 512]);
    __syncthreads();

    int cur = 0;
    for (int k0 = 0; k0 < K; k0 += 32) {
        if (k0 + 32 < K) {
            const int nk = k0 + 32, nb = cur ^ 1;
            gload_lds16(&A   [(size_t)(m0 + r0) * K + nk + col0], &As0[nb * 4096 + (w * 2 + 0) * 512]);
            gload_lds16(&A   [(size_t)(m0 + r1) * K + nk + col1], &As0[nb * 4096 + (w * 2 + 1) * 512]);
            gload_lds16(&Brow[(size_t)r0 * K + nk + col0],        &Bs0[nb * 4096 + (w * 2 + 0) * 512]);
            gload_lds16(&Brow[(size_t)r1 * K + nk + col1],        &Bs0[nb * 4096 + (w * 2 + 1) * 512]);
        }
        bf16x8_t af[4], bfr[4];
#pragma unroll
        for (int m = 0; m < 4; ++m)
            af[m] = *reinterpret_cast<const bf16x8_t*>(&As0[cur * 4096 + (wm * 64 + m * 16 + r) * 32 + sw]);
#pragma unroll
        for (int n = 0; n < 4; ++n)
            bfr[n] = *reinterpret_cast<const bf16x8_t*>(&Bs0[cur * 4096 + (wn * 64 + n * 16 + r) * 32 + sw]);
#pragma unroll
        for (int m = 0; m < 4; ++m)
#pragma unroll
            for (int n = 0; n < 4; ++n)
                acc[m][n] = __builtin_amdgcn_mfma_f32_16x16x32_bf16(af[m], bfr[n], acc[m][n], 0, 0, 0);
        __syncthreads();
        cur ^= 1;
    }

    if (n0 < 5120) {
        // ---- Q or K tile: stage 128x128 bf16 in flat LDS, rope pairs (d, d+64), store ----
#pragma unroll
        for (int m = 0; m < 4; ++m)
#pragma unroll
            for (int n = 0; n < 4; ++n)
#pragma unroll
                for (int j = 0; j < 4; ++j)
                    LDS[(wm * 64 + m * 16 + g * 4 + j) * 128 + wn * 64 + n * 16 + r] = f2bf(acc[m][n][j]);
        __syncthreads();
        unsigned short* dst; int ldd, coff;
        if (n0 < 4096) { dst = Qb; ldd = 4096; coff = n0; }
        else           { dst = Kb; ldd = 1024; coff = n0 - 4096; }
        for (int i = tid; i < 8192; i += 256) {
            int row = i >> 6, dlo = i & 63;
            int tok = m0 + row;
            float a  = bf2f(LDS[row * 128 + dlo]);
            float b  = bf2f(LDS[row * 128 + 64 + dlo]);
            float c  = tb[tok * 128 + dlo];
            float sn = tb[tok * 128 + 64 + dlo];
            dst[(size_t)tok * ldd + coff + dlo]      = f2bf(a * c - b * sn);
            dst[(size_t)tok * ldd + coff + 64 + dlo] = f2bf(b * c + a * sn);
        }
    } else {
        // ---- V tile: write transposed ----
#pragma unroll
        for (int m = 0; m < 4; ++m)
#pragma unroll
            for (int n = 0; n < 4; ++n) {
                int col  = n0 + wn * 64 + n * 16 + r;
                int row0 = m0 + wm * 64 + m * 16 + g * 4;
                int d = col - 5120;
                int b = row0 >> 10, tokl = row0 & 1023;
                uint2 o;
                o.x = (unsigned)f2bf(acc[m][n][0]) | ((unsigned)f2bf(acc[m][n][1]) << 16);
                o.y = (unsigned)f2bf(acc[m][n][2]) | ((unsigned)f2bf(acc[m][n][3]) << 16);
                *reinterpret_cast<uint2*>(&VT[(size_t)(b * 1024 + d) * 1024 + tokl]) = o;
            }
    }
}

// ---------------- attn (4 indep waves/block, barrier-free, in-place out over Q) ∥ tcvt(wo) ----------------
__global__ __launch_bounds__(256) void attn_tcvt(
    unsigned short* __restrict__ Qb,         // [2048][4096] roped Q, overwritten with attn out
    const unsigned short* __restrict__ Kb,   // [2048][1024]
    const unsigned short* __restrict__ VT,   // [2048][1024]
    const float* __restrict__ wo,
    unsigned short* __restrict__ woT)
{
    const int bid = blockIdx.x;
    const int tid = threadIdx.x;
    __shared__ unsigned short P_lds[4][32][40];
    __shared__ unsigned short Lt[32][36];

    if (bid >= 512) {                         // tcvt wo -> woT (128 x 128 tiles)
        int q = bid - 512;
        tcvt_body(wo, woT, 4096, q & 127, q >> 7, Lt, tid);
        return;
    }

    // ---- attention: wave wid handles q-tile qt = 31 - (qtg + wid*8) ----
    const int wid  = tid >> 6;
    const int lane = tid & 63;
    const int h    = bid & 31;
    const int tmp  = bid >> 5;
    const int qtg  = tmp & 7;
    const int b    = tmp >> 3;
    const int qt   = 31 - (qtg + wid * 8);    // heavy-first
    const int kvh  = h >> 2;
    const int r = lane & 15, g = lane >> 4;

    const int qrow0 = qt * 32;
    unsigned short* Qp = Qb + ((size_t)(b * S_) + qrow0) * 4096 + h * 128;
    bf16x8_t qf[2][4];
#pragma unroll
    for (int q2 = 0; q2 < 2; ++q2)
#pragma unroll
        for (int kk = 0; kk < 4; ++kk)
            qf[q2][kk] = *reinterpret_cast<const bf16x8_t*>(
                &Qp[(size_t)(q2 * 16 + r) * 4096 + kk * 32 + g * 8]);

    const f32x4_t zero = {0.f, 0.f, 0.f, 0.f};
    f32x4_t o[2][8];
#pragma unroll
    for (int q2 = 0; q2 < 2; ++q2)
#pragma unroll
        for (int n = 0; n < 8; ++n) o[q2][n] = zero;
    float m_[2][4], s_[2][4];
#pragma unroll
    for (int q2 = 0; q2 < 2; ++q2)
#pragma unroll
        for (int j = 0; j < 4; ++j) { m_[q2][j] = -1e30f; s_[q2][j] = 0.f; }

    const float scale = 0.08838834764831845f;   // 1/sqrt(128)
    const unsigned short* Kp = Kb + (size_t)(b * S_) * 1024 + kvh * 128;
    const unsigned short* Vt = VT + ((size_t)(b * 1024) + kvh * 128) * 1024;
    const int ntiles = qt + 1;

    for (int t = 0; t < ntiles; ++t) {
        const int k0 = t << 5;
        f32x4_t sc[2][2];
        sc[0][0] = zero; sc[0][1] = zero; sc[1][0] = zero; sc[1][1] = zero;
        __builtin_amdgcn_s_setprio(1);
#pragma unroll
        for (int kk = 0; kk < 4; ++kk) {
            bf16x8_t kf0 = *reinterpret_cast<const bf16x8_t*>(
                &Kp[(size_t)(k0 + r) * 1024 + kk * 32 + g * 8]);
            bf16x8_t kf1 = *reinterpret_cast<const bf16x8_t*>(
                &Kp[(size_t)(k0 + 16 + r) * 1024 + kk * 32 + g * 8]);
#pragma unroll
            for (int q2 = 0; q2 < 2; ++q2) {
                sc[q2][0] = __builtin_amdgcn_mfma_f32_16x16x32_bf16(qf[q2][kk], kf0, sc[q2][0], 0, 0, 0);
                sc[q2][1] = __builtin_amdgcn_mfma_f32_16x16x32_bf16(qf[q2][kk], kf1, sc[q2][1], 0, 0, 0);
            }
        }
        __builtin_amdgcn_s_setprio(0);
        bf16x8_t vf[8];
#pragma unroll
        for (int n = 0; n < 8; ++n)
            vf[n] = *reinterpret_cast<const bf16x8_t*>(
                &Vt[(size_t)(n * 16 + r) * 1024 + k0 + g * 8]);
        float al[2][4];
#pragma unroll
        for (int q2 = 0; q2 < 2; ++q2)
#pragma unroll
            for (int j = 0; j < 4; ++j) {
                int row = qrow0 + q2 * 16 + g * 4 + j;
                float v0 = sc[q2][0][j] * scale + ((k0 + r)      > row ? -1e9f : 0.f);
                float v1 = sc[q2][1][j] * scale + ((k0 + 16 + r) > row ? -1e9f : 0.f);
                float mx = fmaxf(v0, v1);
#pragma unroll
                for (int off = 1; off < 16; off <<= 1)
                    mx = fmaxf(mx, __shfl_xor(mx, off));
                float mn = fmaxf(m_[q2][j], mx);
                al[q2][j] = __expf(m_[q2][j] - mn);
                float p0 = __expf(v0 - mn);
                float p1 = __expf(v1 - mn);
                float rs = p0 + p1;
#pragma unroll
                for (int off = 1; off < 16; off <<= 1)
                    rs += __shfl_xor(rs, off);
                s_[q2][j] = s_[q2][j] * al[q2][j] + rs;
                m_[q2][j] = mn;
                P_lds[wid][q2 * 16 + g * 4 + j][r]      = f2bf(p0);
                P_lds[wid][q2 * 16 + g * 4 + j][16 + r] = f2bf(p1);
            }
#pragma unroll
        for (int q2 = 0; q2 < 2; ++q2)
#pragma unroll
            for (int n = 0; n < 8; ++n)
#pragma unroll
                for (int j = 0; j < 4; ++j)
                    o[q2][n][j] *= al[q2][j];
        // single-wave LDS round-trip: compiler-ordered via lgkmcnt, no barrier needed
        bf16x8_t pa[2];
        pa[0] = *reinterpret_cast<const bf16x8_t*>(&P_lds[wid][r][g * 8]);
        pa[1] = *reinterpret_cast<const bf16x8_t*>(&P_lds[wid][16 + r][g * 8]);
        __builtin_amdgcn_s_setprio(1);
#pragma unroll
        for (int n = 0; n < 8; ++n)
#pragma unroll
            for (int q2 = 0; q2 < 2; ++q2)
                o[q2][n] = __builtin_amdgcn_mfma_f32_16x16x32_bf16(pa[q2], vf[n], o[q2][n], 0, 0, 0);
        __builtin_amdgcn_s_setprio(0);
    }
    // ---- epilogue: in-place over this wave's own Q region (read once, above) ----
#pragma unroll
    for (int q2 = 0; q2 < 2; ++q2)
#pragma unroll
        for (int n = 0; n < 8; ++n)
#pragma unroll
            for (int j = 0; j < 4; ++j) {
                float val = o[q2][n][j] / s_[q2][j];
                Qp[(size_t)(q2 * 16 + g * 4 + j) * 4096 + n * 16 + r] = f2bf(val);
            }
}

// ---------------- O-proj GEMM: 2-phase dbuf + chunk swizzle + XCD remap ----------------
__global__ __launch_bounds__(256) void gemm_tt(
    const unsigned short* __restrict__ A,
    const unsigned short* __restrict__ Bt,
    float* __restrict__ Cm,
    int ldc, int K)
{
    __shared__ unsigned short As[2][128 * 32];
    __shared__ unsigned short Bs[2][128 * 32];
    const int tid  = threadIdx.x;
    const int lane = tid & 63;
    const int w    = tid >> 6;
    const int wm   = w >> 1, wn = w & 1;
    const int r    = lane & 15, g = lane >> 4;

    const int nwg = gridDim.x * gridDim.y;
    const int D   = blockIdx.y * gridDim.x + blockIdx.x;
    const int L   = (D & 7) * (nwg >> 3) + (D >> 3);
    const int m0  = (L / gridDim.x) * 128, n0 = (L % gridDim.x) * 128;

    const int c0 = w * 128 + lane;
    const int c1 = c0 + 64;
    const int r0 = c0 >> 2, col0 = (((c0 & 3) ^ (r0 & 3)) << 3);
    const int r1 = c1 >> 2, col1 = (((c1 & 3) ^ (r1 & 3)) << 3);
    const int sw = (g ^ (r & 3)) << 3;

    const f32x4_t zero = {0.f, 0.f, 0.f, 0.f};
    f32x4_t acc[4][4];
#pragma unroll
    for (int i = 0; i < 4; ++i)
#pragma unroll
        for (int j = 0; j < 4; ++j) acc[i][j] = zero;

    gload_lds16(&A [(size_t)(m0 + r0) * K + col0], &As[0][(w * 2 + 0) * 512]);
    gload_lds16(&A [(size_t)(m0 + r1) * K + col1], &As[0][(w * 2 + 1) * 512]);
    gload_lds16(&Bt[(size_t)(n0 + r0) * K + col0], &Bs[0][(w * 2 + 0) * 512]);
    gload_lds16(&Bt[(size_t)(n0 + r1) * K + col1], &Bs[0][(w * 2 + 1) * 512]);
    __syncthreads();

    int cur = 0;
    for (int k0 = 0; k0 < K; k0 += 32) {
        if (k0 + 32 < K) {
            const int nk = k0 + 32, nb = cur ^ 1;
            gload_lds16(&A [(size_t)(m0 + r0) * K + nk + col0], &As[nb][(w * 2 + 0) * 512]);
            gload_lds16(&A [(size_t)(m0 + r1) * K + nk + col1], &As[nb][(w * 2 + 1) * 512]);
            gload_lds16(&Bt[(size_t)(n0 + r0) * K + nk + col0], &Bs[nb][(w * 2 + 0) * 512]);
            gload_lds16(&Bt[(size_t)(n0 + r1) * K + nk + col1], &Bs[nb][(w * 2 + 1) * 512]);
        }
        bf16x8_t af[4], bfr[4];
#pragma unroll
        for (int m = 0; m < 4; ++m)
            af[m] = *reinterpret_cast<const bf16x8_t*>(&As[cur][(wm * 64 + m * 16 + r) * 32 + sw]);
#pragma unroll
        for (int n = 0; n < 4; ++n)
            bfr[n] = *reinterpret_cast<const bf16x8_t*>(&Bs[cur][(wn * 64 + n * 16 + r) * 32 + sw]);
#pragma unroll
        for (int m = 0; m < 4; ++m)
#pragma unroll
            for (int n = 0; n < 4; ++n)
                acc[m][n] = __builtin_amdgcn_mfma_f32_16x16x32_bf16(af[m], bfr[n], acc[m][n], 0, 0, 0);
        __syncthreads();
        cur ^= 1;
    }

#pragma unroll
    for (int m = 0; m < 4; ++m)
#pragma unroll
        for (int n = 0; n < 4; ++n)
#pragma unroll
            for (int j = 0; j < 4; ++j) {
                int row = m0 + wm * 64 + m * 16 + g * 4 + j;
                int col = n0 + wn * 64 + n * 16 + r;
                Cm[(size_t)row * ldc + col] = acc[m][n][j];
            }
}

// ---------------- launcher: 4 dispatches ----------------
extern "C" void kernel_launch(void* const* d_in, const int* in_sizes, int n_in,
                              void* d_out, int out_size, void* d_ws, size_t ws_size,
                              hipStream_t stream)
{
    const float* x  = (const float*)d_in[0];
    const float* wq = (const float*)d_in[2];
    const float* wk = (const float*)d_in[3];
    const float* wv = (const float*)d_in[4];
    const float* wo = (const float*)d_in[5];
    const int* start_pos = (const int*)d_in[10];

    char* ws = (char*)d_ws;
    unsigned short* qb   = (unsigned short*)(ws);                   // [0,16M)  Q (roped), attn out in-place
    unsigned short* kb   = (unsigned short*)(ws + (16u << 20));     // [16,20M) K (roped)
    unsigned short* vT   = (unsigned short*)(ws + (20u << 20));     // [20,24M) V^T
    unsigned short* xb   = (unsigned short*)(ws + (24u << 20));     // [24,40M) x bf16 (dead after qkv)
    unsigned short* wkvT = (unsigned short*)(ws + (40u << 20));     // [40,56M) wk^T|wv^T (dead after qkv)
    float*          tb   = (float*)(ws + (56u << 20));              // [56,57M) rope table
    unsigned short* wqT  = (unsigned short*)d_out;                  // 32 MB scratch until final store
    unsigned short* woT  = xb;                                      // [24,56M): 32 MB over dead xb+wkvT

    // 1) prep: x->bf16, wq^T, wk^T, wv^T, rope table   (33280 blocks, routed)
    prep<<<33280, 256, 0, stream>>>(x, wq, wk, wv, start_pos, xb, wqT, wkvT, tb);

    // 2) fused QKV projection (N=6144) + RoPE epilogue; V written transposed
    gemm_qkv<<<dim3(48, 16), 256, 0, stream>>>(xb, wqT, wkvT, tb, qb, kb, vT, HID_);

    // 3) causal GQA flash attention (in-place over Q) ∥ wo^T transpose
    attn_tcvt<<<512 + 16384, 256, 0, stream>>>(qb, kb, vT, wo, woT);

    // 4) output projection -> fp32 d_out
    gemm_tt<<<dim3(32, 16), 256, 0, stream>>>(qb, woT, (float*)d_out, 4096, HID_);
}

// Round 7
// 596.411 us; speedup vs baseline: 1.1009x; 1.1009x over previous
//
#include <hip/hip_runtime.h>
#include <hip/hip_bf16.h>

#define B_    2
#define S_    1024
#define HID_  4096
#define H_    32
#define HKV_  8
#define HD_   128

typedef __attribute__((ext_vector_type(8))) short   bf16x8_t;
typedef __attribute__((ext_vector_type(4))) float   f32x4_t;

__device__ __forceinline__ unsigned short f2bf(float f) {
    union { float f; unsigned u; } v; v.f = f;
    unsigned r = v.u + 0x7fffu + ((v.u >> 16) & 1u);
    return (unsigned short)(r >> 16);
}
__device__ __forceinline__ float bf2f(unsigned short u) {
    union { unsigned u; float f; } v; v.u = ((unsigned)u) << 16;
    return v.f;
}

__device__ __forceinline__ void gload_lds16(const void* g, void* l) {
    __builtin_amdgcn_global_load_lds(
        (const __attribute__((address_space(1))) unsigned int*)g,
        (__attribute__((address_space(3))) unsigned int*)l, 16, 0, 0);
}

// 32x32 transpose+convert tile body (W fp32 [K][ldW] -> Wt bf16 [n][4096])
__device__ __forceinline__ void tcvt_body(const float* __restrict__ W,
                                          unsigned short* __restrict__ Wt,
                                          int ldW, int nb, int kb,
                                          unsigned short (*L)[36], int t) {
    {
        int kr = t >> 3, nc = (t & 7) * 4;
        float4 v = *reinterpret_cast<const float4*>(&W[(size_t)(kb * 32 + kr) * ldW + nb * 32 + nc]);
        L[nc + 0][kr] = f2bf(v.x);
        L[nc + 1][kr] = f2bf(v.y);
        L[nc + 2][kr] = f2bf(v.z);
        L[nc + 3][kr] = f2bf(v.w);
    }
    __syncthreads();
    {
        int nr = t >> 3, kc = (t & 7) * 4;
        uint2 o;
        o.x = (unsigned)L[nr][kc + 0] | ((unsigned)L[nr][kc + 1] << 16);
        o.y = (unsigned)L[nr][kc + 2] | ((unsigned)L[nr][kc + 3] << 16);
        *reinterpret_cast<uint2*>(&Wt[(size_t)(nb * 32 + nr) * 4096 + kb * 32 + kc]) = o;
    }
}

// ---------------- prep: cvt(x) | tcvt(wq) | tcvt(wk) | tcvt(wv) | rope table ----------------
__global__ __launch_bounds__(256) void prep(
    const float* __restrict__ x,  const float* __restrict__ wq,
    const float* __restrict__ wk, const float* __restrict__ wv,
    const int* __restrict__ start_pos,
    unsigned short* __restrict__ xb, unsigned short* __restrict__ wqT,
    unsigned short* __restrict__ wkvT, float* __restrict__ tb)
{
    const int bid = blockIdx.x;
    const int t   = threadIdx.x;
    if (bid < 8192) {                         // x fp32 -> bf16  (2048*4096/4 float4s)
        int i = bid * 256 + t;
        float4 v = reinterpret_cast<const float4*>(x)[i];
        uint2 p;
        p.x = (unsigned)f2bf(v.x) | ((unsigned)f2bf(v.y) << 16);
        p.y = (unsigned)f2bf(v.z) | ((unsigned)f2bf(v.w) << 16);
        reinterpret_cast<uint2*>(xb)[i] = p;
        return;
    }
    if (bid >= 32768) {                       // rope table: 512 blocks = 2048 tok * 64 d
        int i = (bid - 32768) * 256 + t;
        int d = i & 63;
        int tok = i >> 6;
        int s = tok & (S_ - 1);
        int b = tok >> 10;
        float pos = (float)(start_pos[b] + s);
        float freq = __expf(-(float)d * (9.210340371976184f / 64.f));   // 10000^(-d/64)
        float ang = pos * freq;
        tb[tok * 128 + d]      = cosf(ang);
        tb[tok * 128 + 64 + d] = sinf(ang);
        return;
    }
    __shared__ unsigned short L[32][36];
    if (bid < 24576) {                        // wq^T (128 x 128 tiles)
        int q = bid - 8192;
        tcvt_body(wq, wqT, 4096, q & 127, q >> 7, L, t);
    } else if (bid < 28672) {                 // wk^T (32 x 128)
        int q = bid - 24576;
        tcvt_body(wk, wkvT, 1024, q & 31, q >> 5, L, t);
    } else {                                  // wv^T (32 x 128)
        int q = bid - 28672;
        tcvt_body(wv, wkvT + (size_t)1024 * 4096, 1024, q & 31, q >> 5, L, t);
    }
}

// ---------------- fused QKV GEMM (N=6144) + RoPE epilogue for Q/K, V^T routing ----------------
__global__ __launch_bounds__(256) void gemm_qkv(
    const unsigned short* __restrict__ A,      // xb [2048][4096]
    const unsigned short* __restrict__ BtQ,    // wqT [4096][4096]
    const unsigned short* __restrict__ BtKV,   // wkvT [2048][4096]
    const float* __restrict__ tb,              // rope table [2048][128]
    unsigned short* __restrict__ Qb,           // [2048][4096] roped
    unsigned short* __restrict__ Kb,           // [2048][1024] roped
    unsigned short* __restrict__ VT,           // [2048][1024] transposed V
    int K)
{
    __shared__ unsigned short LDS[16384];      // As[2][4096] | Bs[2][4096]; flat 128x128 in epilogue
    unsigned short* As0 = LDS;
    unsigned short* Bs0 = LDS + 8192;
    const int tid  = threadIdx.x;
    const int lane = tid & 63;
    const int w    = tid >> 6;
    const int wm   = w >> 1, wn = w & 1;
    const int r    = lane & 15, g = lane >> 4;

    const int nwg = gridDim.x * gridDim.y;
    const int D   = blockIdx.y * gridDim.x + blockIdx.x;
    const int L   = (D & 7) * (nwg >> 3) + (D >> 3);
    const int m0  = (L / gridDim.x) * 128, n0 = (L % gridDim.x) * 128;

    const unsigned short* Brow = (n0 < 4096) ? (BtQ + (size_t)n0 * K)
                                             : (BtKV + (size_t)(n0 - 4096) * K);

    const int c0 = w * 128 + lane;
    const int c1 = c0 + 64;
    const int r0 = c0 >> 2, col0 = (((c0 & 3) ^ (r0 & 3)) << 3);
    const int r1 = c1 >> 2, col1 = (((c1 & 3) ^ (r1 & 3)) << 3);
    const int sw = (g ^ (r & 3)) << 3;

    const f32x4_t zero = {0.f, 0.f, 0.f, 0.f};
    f32x4_t acc[4][4];
#pragma unroll
    for (int i = 0; i < 4; ++i)
#pragma unroll
        for (int j = 0; j < 4; ++j) acc[i][j] = zero;

    gload_lds16(&A   [(size_t)(m0 + r0) * K + col0], &As0[(w * 2 + 0) * 512]);
    gload_lds16(&A   [(size_t)(m0 + r1) * K + col1], &As0[(w * 2 + 1) * 512]);
    gload_lds16(&Brow[(size_t)r0 * K + col0],        &Bs0[(w * 2 + 0) * 512]);
    gload_lds16(&Brow[(size_t)r1 * K + col1],        &Bs0[(w * 2 + 1) * 512]);
    __syncthreads();

    int cur = 0;
    for (int k0 = 0; k0 < K; k0 += 32) {
        if (k0 + 32 < K) {
            const int nk = k0 + 32, nb = cur ^ 1;
            gload_lds16(&A   [(size_t)(m0 + r0) * K + nk + col0], &As0[nb * 4096 + (w * 2 + 0) * 512]);
            gload_lds16(&A   [(size_t)(m0 + r1) * K + nk + col1], &As0[nb * 4096 + (w * 2 + 1) * 512]);
            gload_lds16(&Brow[(size_t)r0 * K + nk + col0],        &Bs0[nb * 4096 + (w * 2 + 0) * 512]);
            gload_lds16(&Brow[(size_t)r1 * K + nk + col1],        &Bs0[nb * 4096 + (w * 2 + 1) * 512]);
        }
        bf16x8_t af[4], bfr[4];
#pragma unroll
        for (int m = 0; m < 4; ++m)
            af[m] = *reinterpret_cast<const bf16x8_t*>(&As0[cur * 4096 + (wm * 64 + m * 16 + r) * 32 + sw]);
#pragma unroll
        for (int n = 0; n < 4; ++n)
            bfr[n] = *reinterpret_cast<const bf16x8_t*>(&Bs0[cur * 4096 + (wn * 64 + n * 16 + r) * 32 + sw]);
#pragma unroll
        for (int m = 0; m < 4; ++m)
#pragma unroll
            for (int n = 0; n < 4; ++n)
                acc[m][n] = __builtin_amdgcn_mfma_f32_16x16x32_bf16(af[m], bfr[n], acc[m][n], 0, 0, 0);
        __syncthreads();
        cur ^= 1;
    }

    if (n0 < 5120) {
        // ---- Q or K tile: stage 128x128 bf16 in flat LDS, rope pairs (d, d+64), store ----
#pragma unroll
        for (int m = 0; m < 4; ++m)
#pragma unroll
            for (int n = 0; n < 4; ++n)
#pragma unroll
                for (int j = 0; j < 4; ++j)
                    LDS[(wm * 64 + m * 16 + g * 4 + j) * 128 + wn * 64 + n * 16 + r] = f2bf(acc[m][n][j]);
        __syncthreads();
        unsigned short* dst; int ldd, coff;
        if (n0 < 4096) { dst = Qb; ldd = 4096; coff = n0; }
        else           { dst = Kb; ldd = 1024; coff = n0 - 4096; }
        for (int i = tid; i < 8192; i += 256) {
            int row = i >> 6, dlo = i & 63;
            int tok = m0 + row;
            float a  = bf2f(LDS[row * 128 + dlo]);
            float b  = bf2f(LDS[row * 128 + 64 + dlo]);
            float c  = tb[tok * 128 + dlo];
            float sn = tb[tok * 128 + 64 + dlo];
            dst[(size_t)tok * ldd + coff + dlo]      = f2bf(a * c - b * sn);
            dst[(size_t)tok * ldd + coff + 64 + dlo] = f2bf(b * c + a * sn);
        }
    } else {
        // ---- V tile: write transposed ----
#pragma unroll
        for (int m = 0; m < 4; ++m)
#pragma unroll
            for (int n = 0; n < 4; ++n) {
                int col  = n0 + wn * 64 + n * 16 + r;
                int row0 = m0 + wm * 64 + m * 16 + g * 4;
                int d = col - 5120;
                int b = row0 >> 10, tokl = row0 & 1023;
                uint2 o;
                o.x = (unsigned)f2bf(acc[m][n][0]) | ((unsigned)f2bf(acc[m][n][1]) << 16);
                o.y = (unsigned)f2bf(acc[m][n][2]) | ((unsigned)f2bf(acc[m][n][3]) << 16);
                *reinterpret_cast<uint2*>(&VT[(size_t)(b * 1024 + d) * 1024 + tokl]) = o;
            }
    }
}

// ---------------- attn (4 balanced waves/block: same qt, 4 q-heads of one kv group) ∥ tcvt(wo) ----------------
__global__ __launch_bounds__(256) void attn_tcvt(
    unsigned short* __restrict__ Qb,         // [2048][4096] roped Q, overwritten with attn out
    const unsigned short* __restrict__ Kb,   // [2048][1024]
    const unsigned short* __restrict__ VT,   // [2048][1024]
    const float* __restrict__ wo,
    unsigned short* __restrict__ woT)
{
    const int bid = blockIdx.x;
    const int tid = threadIdx.x;
    __shared__ unsigned short P_lds[4][32][40];
    __shared__ unsigned short Lt[32][36];

    if (bid >= 512) {                         // tcvt wo -> woT (128 x 128 tiles)
        int q = bid - 512;
        tcvt_body(wo, woT, 4096, q & 127, q >> 7, Lt, tid);
        return;
    }

    // ---- attention: all 4 waves share (b, kvh, qt); wave wid = q-head kvh*4+wid ----
    const int wid  = tid >> 6;
    const int lane = tid & 63;
    const int kvh  = bid & 7;
    const int qt   = 31 - ((bid >> 3) & 31);  // heavy-first
    const int b    = bid >> 8;
    const int h    = kvh * 4 + wid;
    const int r = lane & 15, g = lane >> 4;

    const int qrow0 = qt * 32;
    unsigned short* Qp = Qb + ((size_t)(b * S_) + qrow0) * 4096 + h * 128;
    bf16x8_t qf[2][4];
#pragma unroll
    for (int q2 = 0; q2 < 2; ++q2)
#pragma unroll
        for (int kk = 0; kk < 4; ++kk)
            qf[q2][kk] = *reinterpret_cast<const bf16x8_t*>(
                &Qp[(size_t)(q2 * 16 + r) * 4096 + kk * 32 + g * 8]);

    const f32x4_t zero = {0.f, 0.f, 0.f, 0.f};
    f32x4_t o[2][8];
#pragma unroll
    for (int q2 = 0; q2 < 2; ++q2)
#pragma unroll
        for (int n = 0; n < 8; ++n) o[q2][n] = zero;
    float m_[2][4], s_[2][4];
#pragma unroll
    for (int q2 = 0; q2 < 2; ++q2)
#pragma unroll
        for (int j = 0; j < 4; ++j) { m_[q2][j] = -1e30f; s_[q2][j] = 0.f; }

    const float scale = 0.08838834764831845f;   // 1/sqrt(128)
    const unsigned short* Kp = Kb + (size_t)(b * S_) * 1024 + kvh * 128;
    const unsigned short* Vt = VT + ((size_t)(b * 1024) + kvh * 128) * 1024;
    const int ntiles = qt + 1;

    for (int t = 0; t < ntiles; ++t) {
        const int k0 = t << 5;
        f32x4_t sc[2][2];
        sc[0][0] = zero; sc[0][1] = zero; sc[1][0] = zero; sc[1][1] = zero;
        __builtin_amdgcn_s_setprio(1);
#pragma unroll
        for (int kk = 0; kk < 4; ++kk) {
            bf16x8_t kf0 = *reinterpret_cast<const bf16x8_t*>(
                &Kp[(size_t)(k0 + r) * 1024 + kk * 32 + g * 8]);
            bf16x8_t kf1 = *reinterpret_cast<const bf16x8_t*>(
                &Kp[(size_t)(k0 + 16 + r) * 1024 + kk * 32 + g * 8]);
#pragma unroll
            for (int q2 = 0; q2 < 2; ++q2) {
                sc[q2][0] = __builtin_amdgcn_mfma_f32_16x16x32_bf16(qf[q2][kk], kf0, sc[q2][0], 0, 0, 0);
                sc[q2][1] = __builtin_amdgcn_mfma_f32_16x16x32_bf16(qf[q2][kk], kf1, sc[q2][1], 0, 0, 0);
            }
        }
        __builtin_amdgcn_s_setprio(0);
        bf16x8_t vf[8];
#pragma unroll
        for (int n = 0; n < 8; ++n)
            vf[n] = *reinterpret_cast<const bf16x8_t*>(
                &Vt[(size_t)(n * 16 + r) * 1024 + k0 + g * 8]);
        float al[2][4];
#pragma unroll
        for (int q2 = 0; q2 < 2; ++q2)
#pragma unroll
            for (int j = 0; j < 4; ++j) {
                int row = qrow0 + q2 * 16 + g * 4 + j;
                float v0 = sc[q2][0][j] * scale + ((k0 + r)      > row ? -1e9f : 0.f);
                float v1 = sc[q2][1][j] * scale + ((k0 + 16 + r) > row ? -1e9f : 0.f);
                float mx = fmaxf(v0, v1);
#pragma unroll
                for (int off = 1; off < 16; off <<= 1)
                    mx = fmaxf(mx, __shfl_xor(mx, off));
                float mn = fmaxf(m_[q2][j], mx);
                al[q2][j] = __expf(m_[q2][j] - mn);
                float p0 = __expf(v0 - mn);
                float p1 = __expf(v1 - mn);
                float rs = p0 + p1;
#pragma unroll
                for (int off = 1; off < 16; off <<= 1)
                    rs += __shfl_xor(rs, off);
                s_[q2][j] = s_[q2][j] * al[q2][j] + rs;
                m_[q2][j] = mn;
                P_lds[wid][q2 * 16 + g * 4 + j][r]      = f2bf(p0);
                P_lds[wid][q2 * 16 + g * 4 + j][16 + r] = f2bf(p1);
            }
#pragma unroll
        for (int q2 = 0; q2 < 2; ++q2)
#pragma unroll
            for (int n = 0; n < 8; ++n)
#pragma unroll
                for (int j = 0; j < 4; ++j)
                    o[q2][n][j] *= al[q2][j];
        // single-wave LDS round-trip: compiler-ordered via lgkmcnt, no barrier needed
        bf16x8_t pa[2];
        pa[0] = *reinterpret_cast<const bf16x8_t*>(&P_lds[wid][r][g * 8]);
        pa[1] = *reinterpret_cast<const bf16x8_t*>(&P_lds[wid][16 + r][g * 8]);
        __builtin_amdgcn_s_setprio(1);
#pragma unroll
        for (int n = 0; n < 8; ++n)
#pragma unroll
            for (int q2 = 0; q2 < 2; ++q2)
                o[q2][n] = __builtin_amdgcn_mfma_f32_16x16x32_bf16(pa[q2], vf[n], o[q2][n], 0, 0, 0);
        __builtin_amdgcn_s_setprio(0);
    }
    // ---- epilogue: in-place over this wave's own Q region (read once, above) ----
#pragma unroll
    for (int q2 = 0; q2 < 2; ++q2)
#pragma unroll
        for (int n = 0; n < 8; ++n)
#pragma unroll
            for (int j = 0; j < 4; ++j) {
                float val = o[q2][n][j] / s_[q2][j];
                Qp[(size_t)(q2 * 16 + g * 4 + j) * 4096 + n * 16 + r] = f2bf(val);
            }
}

// ---------------- O-proj GEMM: 2-phase dbuf + chunk swizzle + XCD remap ----------------
__global__ __launch_bounds__(256) void gemm_tt(
    const unsigned short* __restrict__ A,
    const unsigned short* __restrict__ Bt,
    float* __restrict__ Cm,
    int ldc, int K)
{
    __shared__ unsigned short As[2][128 * 32];
    __shared__ unsigned short Bs[2][128 * 32];
    const int tid  = threadIdx.x;
    const int lane = tid & 63;
    const int w    = tid >> 6;
    const int wm   = w >> 1, wn = w & 1;
    const int r    = lane & 15, g = lane >> 4;

    const int nwg = gridDim.x * gridDim.y;
    const int D   = blockIdx.y * gridDim.x + blockIdx.x;
    const int L   = (D & 7) * (nwg >> 3) + (D >> 3);
    const int m0  = (L / gridDim.x) * 128, n0 = (L % gridDim.x) * 128;

    const int c0 = w * 128 + lane;
    const int c1 = c0 + 64;
    const int r0 = c0 >> 2, col0 = (((c0 & 3) ^ (r0 & 3)) << 3);
    const int r1 = c1 >> 2, col1 = (((c1 & 3) ^ (r1 & 3)) << 3);
    const int sw = (g ^ (r & 3)) << 3;

    const f32x4_t zero = {0.f, 0.f, 0.f, 0.f};
    f32x4_t acc[4][4];
#pragma unroll
    for (int i = 0; i < 4; ++i)
#pragma unroll
        for (int j = 0; j < 4; ++j) acc[i][j] = zero;

    gload_lds16(&A [(size_t)(m0 + r0) * K + col0], &As[0][(w * 2 + 0) * 512]);
    gload_lds16(&A [(size_t)(m0 + r1) * K + col1], &As[0][(w * 2 + 1) * 512]);
    gload_lds16(&Bt[(size_t)(n0 + r0) * K + col0], &Bs[0][(w * 2 + 0) * 512]);
    gload_lds16(&Bt[(size_t)(n0 + r1) * K + col1], &Bs[0][(w * 2 + 1) * 512]);
    __syncthreads();

    int cur = 0;
    for (int k0 = 0; k0 < K; k0 += 32) {
        if (k0 + 32 < K) {
            const int nk = k0 + 32, nb = cur ^ 1;
            gload_lds16(&A [(size_t)(m0 + r0) * K + nk + col0], &As[nb][(w * 2 + 0) * 512]);
            gload_lds16(&A [(size_t)(m0 + r1) * K + nk + col1], &As[nb][(w * 2 + 1) * 512]);
            gload_lds16(&Bt[(size_t)(n0 + r0) * K + nk + col0], &Bs[nb][(w * 2 + 0) * 512]);
            gload_lds16(&Bt[(size_t)(n0 + r1) * K + nk + col1], &Bs[nb][(w * 2 + 1) * 512]);
        }
        bf16x8_t af[4], bfr[4];
#pragma unroll
        for (int m = 0; m < 4; ++m)
            af[m] = *reinterpret_cast<const bf16x8_t*>(&As[cur][(wm * 64 + m * 16 + r) * 32 + sw]);
#pragma unroll
        for (int n = 0; n < 4; ++n)
            bfr[n] = *reinterpret_cast<const bf16x8_t*>(&Bs[cur][(wn * 64 + n * 16 + r) * 32 + sw]);
#pragma unroll
        for (int m = 0; m < 4; ++m)
#pragma unroll
            for (int n = 0; n < 4; ++n)
                acc[m][n] = __builtin_amdgcn_mfma_f32_16x16x32_bf16(af[m], bfr[n], acc[m][n], 0, 0, 0);
        __syncthreads();
        cur ^= 1;
    }

#pragma unroll
    for (int m = 0; m < 4; ++m)
#pragma unroll
        for (int n = 0; n < 4; ++n)
#pragma unroll
            for (int j = 0; j < 4; ++j) {
                int row = m0 + wm * 64 + m * 16 + g * 4 + j;
                int col = n0 + wn * 64 + n * 16 + r;
                Cm[(size_t)row * ldc + col] = acc[m][n][j];
            }
}

// ---------------- launcher: 4 dispatches ----------------
extern "C" void kernel_launch(void* const* d_in, const int* in_sizes, int n_in,
                              void* d_out, int out_size, void* d_ws, size_t ws_size,
                              hipStream_t stream)
{
    const float* x  = (const float*)d_in[0];
    const float* wq = (const float*)d_in[2];
    const float* wk = (const float*)d_in[3];
    const float* wv = (const float*)d_in[4];
    const float* wo = (const float*)d_in[5];
    const int* start_pos = (const int*)d_in[10];

    char* ws = (char*)d_ws;
    unsigned short* qb   = (unsigned short*)(ws);                   // [0,16M)  Q (roped), attn out in-place
    unsigned short* kb   = (unsigned short*)(ws + (16u << 20));     // [16,20M) K (roped)
    unsigned short* vT   = (unsigned short*)(ws + (20u << 20));     // [20,24M) V^T
    unsigned short* xb   = (unsigned short*)(ws + (24u << 20));     // [24,40M) x bf16 (dead after qkv)
    unsigned short* wkvT = (unsigned short*)(ws + (40u << 20));     // [40,56M) wk^T|wv^T (dead after qkv)
    float*          tb   = (float*)(ws + (56u << 20));              // [56,57M) rope table
    unsigned short* wqT  = (unsigned short*)d_out;                  // 32 MB scratch until final store
    unsigned short* woT  = xb;                                      // [24,56M): 32 MB over dead xb+wkvT

    // 1) prep: x->bf16, wq^T, wk^T, wv^T, rope table   (33280 blocks, routed)
    prep<<<33280, 256, 0, stream>>>(x, wq, wk, wv, start_pos, xb, wqT, wkvT, tb);

    // 2) fused QKV projection (N=6144) + RoPE epilogue; V written transposed
    gemm_qkv<<<dim3(48, 16), 256, 0, stream>>>(xb, wqT, wkvT, tb, qb, kb, vT, HID_);

    // 3) causal GQA flash attention (balanced 4-wave blocks, in-place over Q) ∥ wo^T transpose
    attn_tcvt<<<512 + 16384, 256, 0, stream>>>(qb, kb, vT, wo, woT);

    // 4) output projection -> fp32 d_out
    gemm_tt<<<dim3(32, 16), 256, 0, stream>>>(qb, woT, (float*)d_out, 4096, HID_);
}